// Round 6
// baseline (367.732 us; speedup 1.0000x reference)
//
#include <hip/hip_runtime.h>
#include <math.h>

// SensorGNN: 2-layer GCN (N=50000, E=800000, F=128, H=64) + flat classifier (6 classes).
// Pipeline: range-count (LDS hist) -> prefix scan -> range-scatter (LDS cursors)
//           -> [gemm+dinv-scale -> csr-aggregate]x2 -> classifier partials -> reduce+softmax.
// All f32. Feature buffers (12.8MB) stay L2/L3 resident for the gather phase.
// Round-3 lesson: 12288 same-line atomicAdds serialized cross-XCD (~160us) -> two-stage reduce.
// Round-4/5 lesson: random global atomic scatter bounces lines across XCDs (52MB HBM writes
//   for a 3.2MB array; ILP didn't help). Fix: dst-range partition, LDS atomics, XCD-local writes.

#define NB_RANGE 64      // range blocks; R = ceil(N/64) = 782 <= 1024 LDS slots
#define RT 1024          // threads per range block (16 waves, 1 block/CU)

// ---------------- graph build: per-range histogram via LDS ----------------

__global__ __launch_bounds__(RT) void range_count(
    const int* __restrict__ dst, int* __restrict__ deg, int N, int E) {
  __shared__ int hist[1024];
  int R = (N + NB_RANGE - 1) / NB_RANGE;
  int lo = blockIdx.x * R;
  int hi = min(lo + R, N);
  int len = hi - lo;
  for (int i = threadIdx.x; i < len; i += RT) hist[i] = 0;
  __syncthreads();
  int E4 = E >> 2;
  const int4* d4 = (const int4*)dst;
  for (int i = threadIdx.x; i < E4; i += RT) {
    int4 d = d4[i];
    if ((unsigned)(d.x - lo) < (unsigned)len) atomicAdd(&hist[d.x - lo], 1);
    if ((unsigned)(d.y - lo) < (unsigned)len) atomicAdd(&hist[d.y - lo], 1);
    if ((unsigned)(d.z - lo) < (unsigned)len) atomicAdd(&hist[d.z - lo], 1);
    if ((unsigned)(d.w - lo) < (unsigned)len) atomicAdd(&hist[d.w - lo], 1);
  }
  for (int e = (E4 << 2) + threadIdx.x; e < E; e += RT) {
    int d = dst[e];
    if ((unsigned)(d - lo) < (unsigned)len) atomicAdd(&hist[d - lo], 1);
  }
  __syncthreads();
  for (int i = threadIdx.x; i < len; i += RT) deg[lo + i] = hist[i];
}

// ---------------- prefix scan over deg -> offs (3 kernels) ----------------

// per-256-chunk exclusive scan; bsum[block]=chunk total; dinv = rsqrt(deg+1) (self loop)
__global__ void scan_block(const int* __restrict__ deg, int* __restrict__ offs,
                           int* __restrict__ bsum, float* __restrict__ dinv, int N) {
  int tid = threadIdx.x, lane = tid & 63, wv = tid >> 6;
  int i = blockIdx.x * 256 + tid;
  int v = (i < N) ? deg[i] : 0;
  if (i < N) dinv[i] = rsqrtf((float)(v + 1));
  int x = v;
#pragma unroll
  for (int d = 1; d < 64; d <<= 1) {
    int y = __shfl_up(x, d, 64);
    if (lane >= d) x += y;
  }
  __shared__ int wtot[4];
  __shared__ int woff[4];
  if (lane == 63) wtot[wv] = x;
  __syncthreads();
  if (tid == 0) {
    int s = 0;
    for (int w = 0; w < 4; ++w) { woff[w] = s; s += wtot[w]; }
    bsum[blockIdx.x] = s;
  }
  __syncthreads();
  if (i < N) offs[i] = x - v + woff[wv];
}

// single block: exclusive-scan bsum[nb] in place (nb <= 256), total -> offs[N]
__global__ void scan_bsums(int* __restrict__ bsum, int* __restrict__ offs, int nb, int N) {
  int tid = threadIdx.x, lane = tid & 63, wv = tid >> 6;
  int v = (tid < nb) ? bsum[tid] : 0;
  int x = v;
#pragma unroll
  for (int d = 1; d < 64; d <<= 1) {
    int y = __shfl_up(x, d, 64);
    if (lane >= d) x += y;
  }
  __shared__ int wtot[4];
  __shared__ int woff[4];
  if (lane == 63) wtot[wv] = x;
  __syncthreads();
  if (tid == 0) {
    int s = 0;
    for (int w = 0; w < 4; ++w) { woff[w] = s; s += wtot[w]; }
  }
  __syncthreads();
  int excl = x - v + woff[wv];
  if (tid < nb) bsum[tid] = excl;
  if (tid == nb - 1) offs[N] = excl + v;
}

__global__ void scan_add(int* __restrict__ offs, const int* __restrict__ bsum, int N) {
  int i = blockIdx.x * 256 + threadIdx.x;
  if (i < N) offs[i] += bsum[blockIdx.x];
}

// ---------------- scatter: LDS cursors, block-exclusive contiguous srt segment ----------

__global__ __launch_bounds__(RT) void range_scatter(
    const int* __restrict__ src, const int* __restrict__ dst,
    const int* __restrict__ offs, int* __restrict__ srt, int N, int E) {
  __shared__ int cur[1024];
  int R = (N + NB_RANGE - 1) / NB_RANGE;
  int lo = blockIdx.x * R;
  int hi = min(lo + R, N);
  int len = hi - lo;
  for (int i = threadIdx.x; i < len; i += RT) cur[i] = offs[lo + i];
  __syncthreads();
  int E4 = E >> 2;
  const int4* d4 = (const int4*)dst;
  const int4* s4 = (const int4*)src;
  for (int i = threadIdx.x; i < E4; i += RT) {
    int4 d = d4[i];
    int4 s = s4[i];
    if ((unsigned)(d.x - lo) < (unsigned)len) srt[atomicAdd(&cur[d.x - lo], 1)] = s.x;
    if ((unsigned)(d.y - lo) < (unsigned)len) srt[atomicAdd(&cur[d.y - lo], 1)] = s.y;
    if ((unsigned)(d.z - lo) < (unsigned)len) srt[atomicAdd(&cur[d.z - lo], 1)] = s.z;
    if ((unsigned)(d.w - lo) < (unsigned)len) srt[atomicAdd(&cur[d.w - lo], 1)] = s.w;
  }
  for (int e = (E4 << 2) + threadIdx.x; e < E; e += RT) {
    int d = dst[e];
    if ((unsigned)(d - lo) < (unsigned)len) srt[atomicAdd(&cur[d - lo], 1)] = src[e];
  }
}

// ---------------- dense transform: G = (X @ W) * dinv[row] ----------------
// block = 256 (4 waves), 32 rows/block, each wave computes 8 rows x 64 cols.
// Unroll capped at 4 to avoid the round-1 VGPR blowup (256 VGPR + 380MB scratch spill).

template <int K, int ROWS>
__global__ __launch_bounds__(256) void gemm_scale(
    const float* __restrict__ X, const float* __restrict__ W,
    const float* __restrict__ dinv, float* __restrict__ G, int N) {
  __shared__ float smw[K * 64];
  __shared__ float xs[ROWS * K];
  int tid = threadIdx.x, lane = tid & 63, wv = tid >> 6;
  for (int idx = tid; idx < K * 16; idx += 256)
    ((float4*)smw)[idx] = ((const float4*)W)[idx];
  int row0 = blockIdx.x * ROWS;
  int base = row0 * K;
  int cnt4 = (min(ROWS * K, N * K - base)) >> 2;  // K%4==0 so exact
  const float4* X4 = (const float4*)(X + base);
  for (int idx = tid; idx < cnt4; idx += 256) ((float4*)xs)[idx] = X4[idx];
  __syncthreads();

  constexpr int RW = ROWS / 4;  // rows per wave
  float acc[RW];
#pragma unroll
  for (int r = 0; r < RW; ++r) acc[r] = 0.f;
  const float* xr = &xs[(wv * RW) * K];
#pragma unroll 4
  for (int k = 0; k < K; ++k) {
    float wval = smw[k * 64 + lane];  // lane-contiguous: 2-way bank alias = free
#pragma unroll
    for (int r = 0; r < RW; ++r) acc[r] = fmaf(xr[r * K + k], wval, acc[r]);  // LDS broadcast
  }
#pragma unroll
  for (int r = 0; r < RW; ++r) {
    int row = row0 + wv * RW + r;
    if (row < N) G[(size_t)row * 64 + lane] = acc[r] * dinv[row];
  }
}

// ---------------- aggregation: H[d] = relu(dinv[d]*(G[d] + sum_{s in in(d)} G[s]) + b) ----
// one wave per node. lane = sub*16 + fl: sub in [0,4) picks which of 4 concurrent edges,
// fl in [0,16) picks the float4 feature quad. 4 edges (4x256B rows) in flight per iteration;
// cross-sub reduce via 2x shfl_xor at the end.

__global__ __launch_bounds__(256) void aggregate(
    const float* __restrict__ G, const int* __restrict__ offs,
    const int* __restrict__ srt, const float* __restrict__ dinv,
    const float* __restrict__ bias, float* __restrict__ H, int N) {
  int lane = threadIdx.x & 63, wv = threadIdx.x >> 6;
  int sub = lane >> 4, fl = lane & 15;
  int node = blockIdx.x * 4 + wv;
  if (node >= N) return;
  const float4* G4 = (const float4*)G;

  // self loop owned by sub 0
  float4 acc;
  if (sub == 0) acc = G4[(size_t)node * 16 + fl];
  else          acc = make_float4(0.f, 0.f, 0.f, 0.f);

  int e = offs[node], e1 = offs[node + 1];
  for (; e + 3 < e1; e += 4) {
    int s = srt[e + sub];                     // 4 distinct ints/wave, broadcast within sub
    float4 g = G4[(size_t)s * 16 + fl];       // 4 rows x 256B fetched concurrently
    acc.x += g.x; acc.y += g.y; acc.z += g.z; acc.w += g.w;
  }
  int rem = e1 - e;
  if (sub < rem) {
    int s = srt[e + sub];
    float4 g = G4[(size_t)s * 16 + fl];
    acc.x += g.x; acc.y += g.y; acc.z += g.z; acc.w += g.w;
  }

  // reduce across the 4 sub groups (lanes fl, fl+16, fl+32, fl+48)
#pragma unroll
  for (int m = 16; m < 64; m <<= 1) {
    acc.x += __shfl_xor(acc.x, m, 64);
    acc.y += __shfl_xor(acc.y, m, 64);
    acc.z += __shfl_xor(acc.z, m, 64);
    acc.w += __shfl_xor(acc.w, m, 64);
  }

  if (sub == 0) {
    float dn = dinv[node];
    const float4* b4 = (const float4*)bias;
    float4 bb = b4[fl];
    float4 r;
    r.x = fmaxf(fmaf(acc.x, dn, bb.x), 0.f);
    r.y = fmaxf(fmaf(acc.y, dn, bb.y), 0.f);
    r.z = fmaxf(fmaf(acc.z, dn, bb.z), 0.f);
    r.w = fmaxf(fmaf(acc.w, dn, bb.w), 0.f);
    ((float4*)H)[(size_t)node * 16 + fl] = r;
  }
}

// ---------------- classifier: part[b][c] = block-partial of sum_i H[i]*Wc[i*6+c] --------
// LCM(4,6)=12: each thread owns 12 consecutive Wc floats (= 2 rows, 3x float4)
// + float2 of H. 12%6==0 -> class pattern per thread is compile-time static.
// NO atomics: per-block partials, reduced by reduce_softmax (round-3: atomic tail was 160us).

__global__ __launch_bounds__(256) void classifier(
    const float* __restrict__ H, const float* __restrict__ Wc,
    float* __restrict__ part, int M12) {
  float a[6] = {0.f, 0.f, 0.f, 0.f, 0.f, 0.f};
  int stride = gridDim.x * blockDim.x;
  for (int g = blockIdx.x * blockDim.x + threadIdx.x; g < M12; g += stride) {
    const float4* w4 = (const float4*)Wc + (size_t)g * 3;
    float4 v0 = w4[0];
    float4 v1 = w4[1];
    float4 v2 = w4[2];
    float2 h = ((const float2*)H)[g];
    a[0] = fmaf(h.x, v0.x, a[0]); a[1] = fmaf(h.x, v0.y, a[1]);
    a[2] = fmaf(h.x, v0.z, a[2]); a[3] = fmaf(h.x, v0.w, a[3]);
    a[4] = fmaf(h.x, v1.x, a[4]); a[5] = fmaf(h.x, v1.y, a[5]);
    a[0] = fmaf(h.y, v1.z, a[0]); a[1] = fmaf(h.y, v1.w, a[1]);
    a[2] = fmaf(h.y, v2.x, a[2]); a[3] = fmaf(h.y, v2.y, a[3]);
    a[4] = fmaf(h.y, v2.z, a[4]); a[5] = fmaf(h.y, v2.w, a[5]);
  }
#pragma unroll
  for (int c = 0; c < 6; ++c) {
    for (int d = 32; d > 0; d >>= 1) a[c] += __shfl_down(a[c], d, 64);
  }
  __shared__ float sh[4][6];
  int lane = threadIdx.x & 63, wv = threadIdx.x >> 6;
  if (lane == 0) {
#pragma unroll
    for (int c = 0; c < 6; ++c) sh[wv][c] = a[c];
  }
  __syncthreads();
  if (threadIdx.x == 0) {
#pragma unroll
    for (int c = 0; c < 6; ++c)
      part[(size_t)blockIdx.x * 6 + c] = sh[0][c] + sh[1][c] + sh[2][c] + sh[3][c];
  }
}

// single block: sum part[nb][6], add bias, softmax, write out[6]
__global__ __launch_bounds__(256) void reduce_softmax(
    const float* __restrict__ part, int nb,
    const float* __restrict__ bc, float* __restrict__ out) {
  int tid = threadIdx.x, lane = tid & 63, wv = tid >> 6;
  float a[6] = {0.f, 0.f, 0.f, 0.f, 0.f, 0.f};
  for (int b = tid; b < nb; b += 256) {
    const float* p = part + (size_t)b * 6;
#pragma unroll
    for (int c = 0; c < 6; ++c) a[c] += p[c];
  }
#pragma unroll
  for (int c = 0; c < 6; ++c) {
    for (int d = 32; d > 0; d >>= 1) a[c] += __shfl_down(a[c], d, 64);
  }
  __shared__ float sh[4][6];
  if (lane == 0) {
#pragma unroll
    for (int c = 0; c < 6; ++c) sh[wv][c] = a[c];
  }
  __syncthreads();
  if (tid == 0) {
    float l[6], m = -1e30f;
#pragma unroll
    for (int c = 0; c < 6; ++c) {
      l[c] = sh[0][c] + sh[1][c] + sh[2][c] + sh[3][c] + bc[c];
      m = fmaxf(m, l[c]);
    }
    float s = 0.f;
#pragma unroll
    for (int c = 0; c < 6; ++c) { l[c] = __expf(l[c] - m); s += l[c]; }
    float inv = 1.f / s;
#pragma unroll
    for (int c = 0; c < 6; ++c) out[c] = l[c] * inv;
  }
}

// ---------------- launch ----------------

static inline size_t align4up(size_t x) { return (x + 3) & ~(size_t)3; }  // 4-elem = 16B

extern "C" void kernel_launch(void* const* d_in, const int* in_sizes, int n_in,
                              void* d_out, int out_size, void* d_ws, size_t ws_size,
                              hipStream_t stream) {
  const float* x  = (const float*)d_in[0];
  const int*   ei = (const int*)d_in[1];
  const float* W1 = (const float*)d_in[2];
  const float* b1 = (const float*)d_in[3];
  const float* W2 = (const float*)d_in[4];
  const float* b2 = (const float*)d_in[5];
  const float* Wc = (const float*)d_in[6];
  const float* bc = (const float*)d_in[7];
  float* out = (float*)d_out;

  const int N = in_sizes[0] / 128;  // 50000
  const int E = in_sizes[1] / 2;    // 800000
  const int* esrc = ei;
  const int* edst = ei + E;
  const int nb = (N + 255) / 256;   // 196 (<=256 required by scan_bsums)
  const int CGRID = 2048;           // classifier blocks

  // 16B-aligned workspace carve
  size_t o = 0;
  int* deg    = (int*)d_ws + o;           o = align4up(o + N);
  int* offs   = (int*)d_ws + o;           o = align4up(o + N + 1);
  int* srt    = (int*)d_ws + o;           o = align4up(o + E);
  int* bsum   = (int*)d_ws + o;           o = align4up(o + nb);
  float* dinv = (float*)d_ws + o;         o = align4up(o + N);
  float* bufA = (float*)d_ws + o;         o = align4up(o + (size_t)N * 64);
  float* bufB = (float*)d_ws + o;         o = align4up(o + (size_t)N * 64);
  float* part = (float*)d_ws + o;         o = align4up(o + (size_t)CGRID * 6);

  range_count<<<NB_RANGE, RT, 0, stream>>>(edst, deg, N, E);
  scan_block<<<nb, 256, 0, stream>>>(deg, offs, bsum, dinv, N);
  scan_bsums<<<1, 256, 0, stream>>>(bsum, offs, nb, N);
  scan_add<<<nb, 256, 0, stream>>>(offs, bsum, N);
  range_scatter<<<NB_RANGE, RT, 0, stream>>>(esrc, edst, offs, srt, N, E);

  gemm_scale<128, 32><<<(N + 31) / 32, 256, 0, stream>>>(x, W1, dinv, bufA, N);
  aggregate<<<(N + 3) / 4, 256, 0, stream>>>(bufA, offs, srt, dinv, b1, bufB, N);
  gemm_scale<64, 32><<<(N + 31) / 32, 256, 0, stream>>>(bufB, W2, dinv, bufA, N);
  aggregate<<<(N + 3) / 4, 256, 0, stream>>>(bufA, offs, srt, dinv, b2, bufB, N);

  // M12 = (N*64*6)/12 = N*32 groups of 12 Wc floats
  classifier<<<CGRID, 256, 0, stream>>>(bufB, Wc, part, N * 32);
  reduce_softmax<<<1, 256, 0, stream>>>(part, CGRID, bc, out);
}

// Round 7
// 194.028 us; speedup vs baseline: 1.8953x; 1.8953x over previous
//
#include <hip/hip_runtime.h>
#include <math.h>

// SensorGNN: 2-layer GCN (N=50000, E=800000, F=128, H=64) + flat classifier (6 classes).
// Graph build = counting sort by dst-range (radix 1024-node ranges):
//   hist_ranges (256 chunk blocks, LDS hist) -> scan_ghist (1 block) ->
//   scatter_ranges (256 chunk blocks, LDS cursors, owner-exclusive writes) ->
//   csr_range (49 range blocks: per-node LDS hist + scan -> dinv/offs/srt).
// Then [gemm+dinv-scale -> csr-aggregate]x2 -> classifier partials -> reduce+softmax.
// Round-3 lesson: same-line global atomics serialize cross-XCD -> two-stage reduce.
// Round-4/5 lesson: random global atomic scatter bounces cache lines via HBM (52MB writes
//   for 3.2MB); ILP can't fix it. Round-6 lesson: range partition w/ full edge replication
//   on 64 blocks = 11% occupancy regression. Fix: partition EDGES across blocks (no
//   replication), LDS-only atomics, owner-exclusive global writes = this counting sort.

#define NCH 256          // edge chunk blocks
#define RBITS 10         // range = 1024 nodes
#define NR_MAX 64

// ---------------- pass A: per-chunk range histograms ----------------

__global__ __launch_bounds__(256) void hist_ranges(
    const int* __restrict__ dst, int* __restrict__ ghist, int NR, int E) {
  __shared__ int h[NR_MAX];
  int tid = threadIdx.x, c = blockIdx.x;
  if (tid < NR) h[tid] = 0;
  __syncthreads();
  int E4 = E >> 2;
  int CH4 = (E4 + NCH - 1) / NCH;
  int i0 = c * CH4, i1 = min(i0 + CH4, E4);
  const int4* d4 = (const int4*)dst;
  for (int i = i0 + tid; i < i1; i += 256) {
    int4 d = d4[i];
    atomicAdd(&h[d.x >> RBITS], 1);
    atomicAdd(&h[d.y >> RBITS], 1);
    atomicAdd(&h[d.z >> RBITS], 1);
    atomicAdd(&h[d.w >> RBITS], 1);
  }
  if (c == NCH - 1) {
    for (int e = (E4 << 2) + tid; e < E; e += 256) atomicAdd(&h[dst[e] >> RBITS], 1);
  }
  __syncthreads();
  if (tid < NR) ghist[tid * NCH + c] = h[tid];  // range-major, chunk-minor
}

// ---------------- pass B: exclusive scan of ghist[NR*NCH] (single block) ----------------

__global__ __launch_bounds__(1024) void scan_ghist(int* __restrict__ g, int M) {
  __shared__ int wtot[16];
  int tid = threadIdx.x, lane = tid & 63, wv = tid >> 6;
  int SEG = (M + 1023) >> 10;
  int base = tid * SEG;
  int s = 0;
  for (int k = 0; k < SEG; ++k) { int i = base + k; if (i < M) s += g[i]; }
  int x = s;
#pragma unroll
  for (int d = 1; d < 64; d <<= 1) { int y = __shfl_up(x, d, 64); if (lane >= d) x += y; }
  if (lane == 63) wtot[wv] = x;
  __syncthreads();
  if (wv == 0 && lane < 16) {
    int t = wtot[lane], xx = t;
#pragma unroll
    for (int d = 1; d < 16; d <<= 1) { int y = __shfl_up(xx, d, 64); if (lane >= d) xx += y; }
    wtot[lane] = xx - t;  // exclusive
  }
  __syncthreads();
  int run = x - s + wtot[wv];
  for (int k = 0; k < SEG; ++k) {
    int i = base + k;
    if (i < M) { int tmp = g[i]; g[i] = run; run += tmp; }
  }
}

// ---------------- pass C: scatter (src,dst) pairs into range-sorted ebuf ----------------

__global__ __launch_bounds__(256) void scatter_ranges(
    const int* __restrict__ src, const int* __restrict__ dst,
    const int* __restrict__ ghist, int2* __restrict__ ebuf, int NR, int E) {
  __shared__ int cur[NR_MAX];
  int tid = threadIdx.x, c = blockIdx.x;
  if (tid < NR) cur[tid] = ghist[tid * NCH + c];
  __syncthreads();
  int E4 = E >> 2;
  int CH4 = (E4 + NCH - 1) / NCH;
  int i0 = c * CH4, i1 = min(i0 + CH4, E4);
  const int4* d4 = (const int4*)dst;
  const int4* s4 = (const int4*)src;
  for (int i = i0 + tid; i < i1; i += 256) {
    int4 d = d4[i];
    int4 s = s4[i];
    ebuf[atomicAdd(&cur[d.x >> RBITS], 1)] = make_int2(s.x, d.x);
    ebuf[atomicAdd(&cur[d.y >> RBITS], 1)] = make_int2(s.y, d.y);
    ebuf[atomicAdd(&cur[d.z >> RBITS], 1)] = make_int2(s.z, d.z);
    ebuf[atomicAdd(&cur[d.w >> RBITS], 1)] = make_int2(s.w, d.w);
  }
  if (c == NCH - 1) {
    for (int e = (E4 << 2) + tid; e < E; e += 256)
      ebuf[atomicAdd(&cur[dst[e] >> RBITS], 1)] = make_int2(src[e], dst[e]);
  }
}

// ---------------- pass D: per-range CSR build (dinv, offs, srt) ----------------

__global__ __launch_bounds__(1024) void csr_range(
    const int2* __restrict__ ebuf, const int* __restrict__ ghist,
    int* __restrict__ offs, int* __restrict__ srt, float* __restrict__ dinv,
    int N, int E, int NR) {
  __shared__ int hist[1024];
  __shared__ int wtot[16];
  int r = blockIdx.x;
  int lo = r << RBITS;
  int len = min(1024, N - lo);
  int tid = threadIdx.x, lane = tid & 63, wv = tid >> 6;
  int S  = ghist[r * NCH];
  int S1 = (r + 1 < NR) ? ghist[(r + 1) * NCH] : E;
  if (tid < len) hist[tid] = 0;
  __syncthreads();
  for (int i = S + tid; i < S1; i += 1024) atomicAdd(&hist[ebuf[i].y - lo], 1);
  __syncthreads();
  int v = (tid < len) ? hist[tid] : 0;
  if (tid < len) dinv[lo + tid] = rsqrtf((float)(v + 1));  // +1 self loop
  // exclusive scan of v across 1024 threads
  int x = v;
#pragma unroll
  for (int d = 1; d < 64; d <<= 1) { int y = __shfl_up(x, d, 64); if (lane >= d) x += y; }
  if (lane == 63) wtot[wv] = x;
  __syncthreads();  // also guarantees all hist reads (v) complete before cursor overwrite
  if (wv == 0 && lane < 16) {
    int t = wtot[lane], xx = t;
#pragma unroll
    for (int d = 1; d < 16; d <<= 1) { int y = __shfl_up(xx, d, 64); if (lane >= d) xx += y; }
    wtot[lane] = xx - t;
  }
  __syncthreads();
  int excl = x - v + wtot[wv];
  if (tid < len) {
    offs[lo + tid] = S + excl;
    hist[tid] = S + excl;  // reuse as cursor
  }
  if (r == 0 && tid == 0) offs[N] = E;
  __syncthreads();
  for (int i = S + tid; i < S1; i += 1024) {
    int2 e = ebuf[i];
    srt[atomicAdd(&hist[e.y - lo], 1)] = e.x;
  }
}

// ---------------- dense transform: G = (X @ W) * dinv[row] ----------------
// block = 256 (4 waves), 32 rows/block, each wave computes 8 rows x 64 cols.
// Unroll capped at 4 to avoid the round-1 VGPR blowup (256 VGPR + 380MB scratch spill).

template <int K, int ROWS>
__global__ __launch_bounds__(256) void gemm_scale(
    const float* __restrict__ X, const float* __restrict__ W,
    const float* __restrict__ dinv, float* __restrict__ G, int N) {
  __shared__ float smw[K * 64];
  __shared__ float xs[ROWS * K];
  int tid = threadIdx.x, lane = tid & 63, wv = tid >> 6;
  for (int idx = tid; idx < K * 16; idx += 256)
    ((float4*)smw)[idx] = ((const float4*)W)[idx];
  int row0 = blockIdx.x * ROWS;
  int base = row0 * K;
  int cnt4 = (min(ROWS * K, N * K - base)) >> 2;  // K%4==0 so exact
  const float4* X4 = (const float4*)(X + base);
  for (int idx = tid; idx < cnt4; idx += 256) ((float4*)xs)[idx] = X4[idx];
  __syncthreads();

  constexpr int RW = ROWS / 4;  // rows per wave
  float acc[RW];
#pragma unroll
  for (int r = 0; r < RW; ++r) acc[r] = 0.f;
  const float* xr = &xs[(wv * RW) * K];
#pragma unroll 4
  for (int k = 0; k < K; ++k) {
    float wval = smw[k * 64 + lane];  // lane-contiguous: 2-way bank alias = free
#pragma unroll
    for (int r = 0; r < RW; ++r) acc[r] = fmaf(xr[r * K + k], wval, acc[r]);  // LDS broadcast
  }
#pragma unroll
  for (int r = 0; r < RW; ++r) {
    int row = row0 + wv * RW + r;
    if (row < N) G[(size_t)row * 64 + lane] = acc[r] * dinv[row];
  }
}

// ---------------- aggregation: H[d] = relu(dinv[d]*(G[d] + sum_{s in in(d)} G[s]) + b) ----
// one wave per node. lane = sub*16 + fl: sub picks 1 of 4 concurrent edges, fl the float4
// feature quad. 4 rows (4x256B) in flight per iteration; cross-sub shfl_xor reduce.

__global__ __launch_bounds__(256) void aggregate(
    const float* __restrict__ G, const int* __restrict__ offs,
    const int* __restrict__ srt, const float* __restrict__ dinv,
    const float* __restrict__ bias, float* __restrict__ H, int N) {
  int lane = threadIdx.x & 63, wv = threadIdx.x >> 6;
  int sub = lane >> 4, fl = lane & 15;
  int node = blockIdx.x * 4 + wv;
  if (node >= N) return;
  const float4* G4 = (const float4*)G;

  float4 acc;
  if (sub == 0) acc = G4[(size_t)node * 16 + fl];  // self loop
  else          acc = make_float4(0.f, 0.f, 0.f, 0.f);

  int e = offs[node], e1 = offs[node + 1];
  for (; e + 3 < e1; e += 4) {
    int s = srt[e + sub];
    float4 g = G4[(size_t)s * 16 + fl];
    acc.x += g.x; acc.y += g.y; acc.z += g.z; acc.w += g.w;
  }
  int rem = e1 - e;
  if (sub < rem) {
    int s = srt[e + sub];
    float4 g = G4[(size_t)s * 16 + fl];
    acc.x += g.x; acc.y += g.y; acc.z += g.z; acc.w += g.w;
  }
#pragma unroll
  for (int m = 16; m < 64; m <<= 1) {
    acc.x += __shfl_xor(acc.x, m, 64);
    acc.y += __shfl_xor(acc.y, m, 64);
    acc.z += __shfl_xor(acc.z, m, 64);
    acc.w += __shfl_xor(acc.w, m, 64);
  }
  if (sub == 0) {
    float dn = dinv[node];
    float4 bb = ((const float4*)bias)[fl];
    float4 r;
    r.x = fmaxf(fmaf(acc.x, dn, bb.x), 0.f);
    r.y = fmaxf(fmaf(acc.y, dn, bb.y), 0.f);
    r.z = fmaxf(fmaf(acc.z, dn, bb.z), 0.f);
    r.w = fmaxf(fmaf(acc.w, dn, bb.w), 0.f);
    ((float4*)H)[(size_t)node * 16 + fl] = r;
  }
}

// ---------------- classifier: part[b][c] = block-partial of sum_i H[i]*Wc[i*6+c] --------
// LCM(4,6)=12: each thread owns 12 consecutive Wc floats (2 rows, 3x float4) + float2 of H.
// NO atomics: per-block partials, reduced by reduce_softmax (round-3: atomic tail was 160us).

__global__ __launch_bounds__(256) void classifier(
    const float* __restrict__ H, const float* __restrict__ Wc,
    float* __restrict__ part, int M12) {
  float a[6] = {0.f, 0.f, 0.f, 0.f, 0.f, 0.f};
  int stride = gridDim.x * blockDim.x;
  for (int g = blockIdx.x * blockDim.x + threadIdx.x; g < M12; g += stride) {
    const float4* w4 = (const float4*)Wc + (size_t)g * 3;
    float4 v0 = w4[0];
    float4 v1 = w4[1];
    float4 v2 = w4[2];
    float2 h = ((const float2*)H)[g];
    a[0] = fmaf(h.x, v0.x, a[0]); a[1] = fmaf(h.x, v0.y, a[1]);
    a[2] = fmaf(h.x, v0.z, a[2]); a[3] = fmaf(h.x, v0.w, a[3]);
    a[4] = fmaf(h.x, v1.x, a[4]); a[5] = fmaf(h.x, v1.y, a[5]);
    a[0] = fmaf(h.y, v1.z, a[0]); a[1] = fmaf(h.y, v1.w, a[1]);
    a[2] = fmaf(h.y, v2.x, a[2]); a[3] = fmaf(h.y, v2.y, a[3]);
    a[4] = fmaf(h.y, v2.z, a[4]); a[5] = fmaf(h.y, v2.w, a[5]);
  }
#pragma unroll
  for (int c = 0; c < 6; ++c) {
    for (int d = 32; d > 0; d >>= 1) a[c] += __shfl_down(a[c], d, 64);
  }
  __shared__ float sh[4][6];
  int lane = threadIdx.x & 63, wv = threadIdx.x >> 6;
  if (lane == 0) {
#pragma unroll
    for (int c = 0; c < 6; ++c) sh[wv][c] = a[c];
  }
  __syncthreads();
  if (threadIdx.x == 0) {
#pragma unroll
    for (int c = 0; c < 6; ++c)
      part[(size_t)blockIdx.x * 6 + c] = sh[0][c] + sh[1][c] + sh[2][c] + sh[3][c];
  }
}

// single block: sum part[nb][6], add bias, softmax, write out[6]
__global__ __launch_bounds__(256) void reduce_softmax(
    const float* __restrict__ part, int nb,
    const float* __restrict__ bc, float* __restrict__ out) {
  int tid = threadIdx.x, lane = tid & 63, wv = tid >> 6;
  float a[6] = {0.f, 0.f, 0.f, 0.f, 0.f, 0.f};
  for (int b = tid; b < nb; b += 256) {
    const float* p = part + (size_t)b * 6;
#pragma unroll
    for (int c = 0; c < 6; ++c) a[c] += p[c];
  }
#pragma unroll
  for (int c = 0; c < 6; ++c) {
    for (int d = 32; d > 0; d >>= 1) a[c] += __shfl_down(a[c], d, 64);
  }
  __shared__ float sh[4][6];
  if (lane == 0) {
#pragma unroll
    for (int c = 0; c < 6; ++c) sh[wv][c] = a[c];
  }
  __syncthreads();
  if (tid == 0) {
    float l[6], m = -1e30f;
#pragma unroll
    for (int c = 0; c < 6; ++c) {
      l[c] = sh[0][c] + sh[1][c] + sh[2][c] + sh[3][c] + bc[c];
      m = fmaxf(m, l[c]);
    }
    float s = 0.f;
#pragma unroll
    for (int c = 0; c < 6; ++c) { l[c] = __expf(l[c] - m); s += l[c]; }
    float inv = 1.f / s;
#pragma unroll
    for (int c = 0; c < 6; ++c) out[c] = l[c] * inv;
  }
}

// ---------------- launch ----------------

static inline size_t align4up(size_t x) { return (x + 3) & ~(size_t)3; }  // 4-elem = 16B

extern "C" void kernel_launch(void* const* d_in, const int* in_sizes, int n_in,
                              void* d_out, int out_size, void* d_ws, size_t ws_size,
                              hipStream_t stream) {
  const float* x  = (const float*)d_in[0];
  const int*   ei = (const int*)d_in[1];
  const float* W1 = (const float*)d_in[2];
  const float* b1 = (const float*)d_in[3];
  const float* W2 = (const float*)d_in[4];
  const float* b2 = (const float*)d_in[5];
  const float* Wc = (const float*)d_in[6];
  const float* bc = (const float*)d_in[7];
  float* out = (float*)d_out;

  const int N = in_sizes[0] / 128;  // 50000
  const int E = in_sizes[1] / 2;    // 800000
  const int* esrc = ei;
  const int* edst = ei + E;
  const int NR = (N + 1023) >> RBITS;  // 49 ranges (<= NR_MAX)
  const int CGRID = 2048;              // classifier blocks

  // 16B-aligned workspace carve
  size_t o = 0;
  int* offs   = (int*)d_ws + o;           o = align4up(o + N + 1);
  int* srt    = (int*)d_ws + o;           o = align4up(o + E);
  float* dinv = (float*)d_ws + o;         o = align4up(o + N);
  int* ghist  = (int*)d_ws + o;           o = align4up(o + (size_t)NR * NCH);
  float* bufA = (float*)d_ws + o;         o = align4up(o + (size_t)N * 64);
  float* bufB = (float*)d_ws + o;         o = align4up(o + (size_t)N * 64);
  float* part = (float*)d_ws + o;         o = align4up(o + (size_t)CGRID * 6);
  int2* ebuf  = (int2*)bufB;  // aliases bufB: dead after csr_range, bufB written by agg1

  hist_ranges<<<NCH, 256, 0, stream>>>(edst, ghist, NR, E);
  scan_ghist<<<1, 1024, 0, stream>>>(ghist, NR * NCH);
  scatter_ranges<<<NCH, 256, 0, stream>>>(esrc, edst, ghist, ebuf, NR, E);
  csr_range<<<NR, 1024, 0, stream>>>(ebuf, ghist, offs, srt, dinv, N, E, NR);

  gemm_scale<128, 32><<<(N + 31) / 32, 256, 0, stream>>>(x, W1, dinv, bufA, N);
  aggregate<<<(N + 3) / 4, 256, 0, stream>>>(bufA, offs, srt, dinv, b1, bufB, N);
  gemm_scale<64, 32><<<(N + 31) / 32, 256, 0, stream>>>(bufB, W2, dinv, bufA, N);
  aggregate<<<(N + 3) / 4, 256, 0, stream>>>(bufA, offs, srt, dinv, b2, bufB, N);

  // M12 = (N*64*6)/12 = N*32 groups of 12 Wc floats
  classifier<<<CGRID, 256, 0, stream>>>(bufB, Wc, part, N * 32);
  reduce_softmax<<<1, 256, 0, stream>>>(part, CGRID, bc, out);
}

// Round 8
// 189.546 us; speedup vs baseline: 1.9401x; 1.0236x over previous
//
#include <hip/hip_runtime.h>
#include <math.h>

// SensorGNN: 2-layer GCN (N=50000, E=800000, F=128, H=64) + flat classifier (6 classes).
// Graph build = counting sort by dst-range (radix 1024-node ranges):
//   hist_ranges (256 chunk blocks, LDS hist) -> scan_ghist (1 block) ->
//   scatter_ranges (256 chunk blocks, LDS cursors, owner-exclusive writes) ->
//   csr_range (49 range blocks: per-node LDS hist + scan -> dinv/offs/srt).
// Then [gemm+dinv-scale -> csr-aggregate]x2 -> classifier partials -> reduce+softmax.
// Round-3 lesson: same-line global atomics serialize cross-XCD -> two-stage reduce.
// Round-4/5 lesson: random global atomic scatter bounces cache lines via HBM; ILP can't fix.
// Round-6 lesson: range partition w/ edge replication = 11% occupancy regression.
// Round-7 lesson: aggregates (~60us each) dominate; srt-load -> G-load dependent chain
//   limits them to ~4 latency rounds/node. Fix: hoist indices to regs + shfl, 8 gathers in flight.

#define NCH 256          // edge chunk blocks
#define RBITS 10         // range = 1024 nodes
#define NR_MAX 64

// ---------------- pass A: per-chunk range histograms ----------------

__global__ __launch_bounds__(256) void hist_ranges(
    const int* __restrict__ dst, int* __restrict__ ghist, int NR, int E) {
  __shared__ int h[NR_MAX];
  int tid = threadIdx.x, c = blockIdx.x;
  if (tid < NR) h[tid] = 0;
  __syncthreads();
  int E4 = E >> 2;
  int CH4 = (E4 + NCH - 1) / NCH;
  int i0 = c * CH4, i1 = min(i0 + CH4, E4);
  const int4* d4 = (const int4*)dst;
  for (int i = i0 + tid; i < i1; i += 256) {
    int4 d = d4[i];
    atomicAdd(&h[d.x >> RBITS], 1);
    atomicAdd(&h[d.y >> RBITS], 1);
    atomicAdd(&h[d.z >> RBITS], 1);
    atomicAdd(&h[d.w >> RBITS], 1);
  }
  if (c == NCH - 1) {
    for (int e = (E4 << 2) + tid; e < E; e += 256) atomicAdd(&h[dst[e] >> RBITS], 1);
  }
  __syncthreads();
  if (tid < NR) ghist[tid * NCH + c] = h[tid];  // range-major, chunk-minor
}

// ---------------- pass B: exclusive scan of ghist[NR*NCH] (single block) ----------------

__global__ __launch_bounds__(1024) void scan_ghist(int* __restrict__ g, int M) {
  __shared__ int wtot[16];
  int tid = threadIdx.x, lane = tid & 63, wv = tid >> 6;
  int SEG = (M + 1023) >> 10;
  int base = tid * SEG;
  int s = 0;
  for (int k = 0; k < SEG; ++k) { int i = base + k; if (i < M) s += g[i]; }
  int x = s;
#pragma unroll
  for (int d = 1; d < 64; d <<= 1) { int y = __shfl_up(x, d, 64); if (lane >= d) x += y; }
  if (lane == 63) wtot[wv] = x;
  __syncthreads();
  if (wv == 0 && lane < 16) {
    int t = wtot[lane], xx = t;
#pragma unroll
    for (int d = 1; d < 16; d <<= 1) { int y = __shfl_up(xx, d, 64); if (lane >= d) xx += y; }
    wtot[lane] = xx - t;  // exclusive
  }
  __syncthreads();
  int run = x - s + wtot[wv];
  for (int k = 0; k < SEG; ++k) {
    int i = base + k;
    if (i < M) { int tmp = g[i]; g[i] = run; run += tmp; }
  }
}

// ---------------- pass C: scatter (src,dst) pairs into range-sorted ebuf ----------------

__global__ __launch_bounds__(256) void scatter_ranges(
    const int* __restrict__ src, const int* __restrict__ dst,
    const int* __restrict__ ghist, int2* __restrict__ ebuf, int NR, int E) {
  __shared__ int cur[NR_MAX];
  int tid = threadIdx.x, c = blockIdx.x;
  if (tid < NR) cur[tid] = ghist[tid * NCH + c];
  __syncthreads();
  int E4 = E >> 2;
  int CH4 = (E4 + NCH - 1) / NCH;
  int i0 = c * CH4, i1 = min(i0 + CH4, E4);
  const int4* d4 = (const int4*)dst;
  const int4* s4 = (const int4*)src;
  for (int i = i0 + tid; i < i1; i += 256) {
    int4 d = d4[i];
    int4 s = s4[i];
    ebuf[atomicAdd(&cur[d.x >> RBITS], 1)] = make_int2(s.x, d.x);
    ebuf[atomicAdd(&cur[d.y >> RBITS], 1)] = make_int2(s.y, d.y);
    ebuf[atomicAdd(&cur[d.z >> RBITS], 1)] = make_int2(s.z, d.z);
    ebuf[atomicAdd(&cur[d.w >> RBITS], 1)] = make_int2(s.w, d.w);
  }
  if (c == NCH - 1) {
    for (int e = (E4 << 2) + tid; e < E; e += 256)
      ebuf[atomicAdd(&cur[dst[e] >> RBITS], 1)] = make_int2(src[e], dst[e]);
  }
}

// ---------------- pass D: per-range CSR build (dinv, offs, srt) ----------------

__global__ __launch_bounds__(1024) void csr_range(
    const int2* __restrict__ ebuf, const int* __restrict__ ghist,
    int* __restrict__ offs, int* __restrict__ srt, float* __restrict__ dinv,
    int N, int E, int NR) {
  __shared__ int hist[1024];
  __shared__ int wtot[16];
  int r = blockIdx.x;
  int lo = r << RBITS;
  int len = min(1024, N - lo);
  int tid = threadIdx.x, lane = tid & 63, wv = tid >> 6;
  int S  = ghist[r * NCH];
  int S1 = (r + 1 < NR) ? ghist[(r + 1) * NCH] : E;
  if (tid < len) hist[tid] = 0;
  __syncthreads();
  for (int i = S + tid; i < S1; i += 1024) atomicAdd(&hist[ebuf[i].y - lo], 1);
  __syncthreads();
  int v = (tid < len) ? hist[tid] : 0;
  if (tid < len) dinv[lo + tid] = rsqrtf((float)(v + 1));  // +1 self loop
  // exclusive scan of v across 1024 threads
  int x = v;
#pragma unroll
  for (int d = 1; d < 64; d <<= 1) { int y = __shfl_up(x, d, 64); if (lane >= d) x += y; }
  if (lane == 63) wtot[wv] = x;
  __syncthreads();  // also guarantees all hist reads (v) complete before cursor overwrite
  if (wv == 0 && lane < 16) {
    int t = wtot[lane], xx = t;
#pragma unroll
    for (int d = 1; d < 16; d <<= 1) { int y = __shfl_up(xx, d, 64); if (lane >= d) xx += y; }
    wtot[lane] = xx - t;
  }
  __syncthreads();
  int excl = x - v + wtot[wv];
  if (tid < len) {
    offs[lo + tid] = S + excl;
    hist[tid] = S + excl;  // reuse as cursor
  }
  if (r == 0 && tid == 0) offs[N] = E;
  __syncthreads();
  for (int i = S + tid; i < S1; i += 1024) {
    int2 e = ebuf[i];
    srt[atomicAdd(&hist[e.y - lo], 1)] = e.x;
  }
}

// ---------------- dense transform: G = (X @ W) * dinv[row] ----------------
// block = 256 (4 waves), 32 rows/block, each wave computes 8 rows x 64 cols.
// Unroll capped at 4 to avoid the round-1 VGPR blowup (256 VGPR + 380MB scratch spill).

template <int K, int ROWS>
__global__ __launch_bounds__(256) void gemm_scale(
    const float* __restrict__ X, const float* __restrict__ W,
    const float* __restrict__ dinv, float* __restrict__ G, int N) {
  __shared__ float smw[K * 64];
  __shared__ float xs[ROWS * K];
  int tid = threadIdx.x, lane = tid & 63, wv = tid >> 6;
  for (int idx = tid; idx < K * 16; idx += 256)
    ((float4*)smw)[idx] = ((const float4*)W)[idx];
  int row0 = blockIdx.x * ROWS;
  int base = row0 * K;
  int cnt4 = (min(ROWS * K, N * K - base)) >> 2;  // K%4==0 so exact
  const float4* X4 = (const float4*)(X + base);
  for (int idx = tid; idx < cnt4; idx += 256) ((float4*)xs)[idx] = X4[idx];
  __syncthreads();

  constexpr int RW = ROWS / 4;  // rows per wave
  float acc[RW];
#pragma unroll
  for (int r = 0; r < RW; ++r) acc[r] = 0.f;
  const float* xr = &xs[(wv * RW) * K];
#pragma unroll 4
  for (int k = 0; k < K; ++k) {
    float wval = smw[k * 64 + lane];  // lane-contiguous: 2-way bank alias = free
#pragma unroll
    for (int r = 0; r < RW; ++r) acc[r] = fmaf(xr[r * K + k], wval, acc[r]);  // LDS broadcast
  }
#pragma unroll
  for (int r = 0; r < RW; ++r) {
    int row = row0 + wv * RW + r;
    if (row < N) G[(size_t)row * 64 + lane] = acc[r] * dinv[row];
  }
}

// ---------------- aggregation: H[d] = relu(dinv[d]*(G[d] + sum_{s in in(d)} G[s]) + b) ----
// one wave per node. lane = sub*16 + fl. Round-8 restructure: all edge indices for
// deg<=64 are hoisted into registers (one coalesced srt load) and distributed via
// dynamic __shfl, so G-row gathers have no memory-dependent index chain; 2x unroll
// keeps 8 independent 256B row-gathers in flight.

__global__ __launch_bounds__(256) void aggregate(
    const float* __restrict__ G, const int* __restrict__ offs,
    const int* __restrict__ srt, const float* __restrict__ dinv,
    const float* __restrict__ bias, float* __restrict__ H, int N) {
  int lane = threadIdx.x & 63, wv = threadIdx.x >> 6;
  int sub = lane >> 4, fl = lane & 15;
  int node = blockIdx.x * 4 + wv;
  if (node >= N) return;
  const float4* G4 = (const float4*)G;

  int e0 = offs[node], e1 = offs[node + 1];
  int deg = e1 - e0;

  float4 accA, accB = make_float4(0.f, 0.f, 0.f, 0.f);
  if (sub == 0) accA = G4[(size_t)node * 16 + fl];  // self loop
  else          accA = make_float4(0.f, 0.f, 0.f, 0.f);

  // hoist up to 64 edge indices into registers (coalesced; covers ~all nodes, mean deg 16)
  int pre = (deg > 0) ? srt[e0 + min(lane, deg - 1)] : 0;

  int dcap = min(deg, 64);
  int base = 0;
  for (; base + 7 < dcap; base += 8) {   // 8 rows in flight, no index-load chain
    int sA = __shfl(pre, base + sub, 64);
    int sB = __shfl(pre, base + 4 + sub, 64);
    float4 gA = G4[(size_t)sA * 16 + fl];
    float4 gB = G4[(size_t)sB * 16 + fl];
    accA.x += gA.x; accA.y += gA.y; accA.z += gA.z; accA.w += gA.w;
    accB.x += gB.x; accB.y += gB.y; accB.z += gB.z; accB.w += gB.w;
  }
  for (; base + 3 < dcap; base += 4) {
    int s = __shfl(pre, base + sub, 64);
    float4 g = G4[(size_t)s * 16 + fl];
    accA.x += g.x; accA.y += g.y; accA.z += g.z; accA.w += g.w;
  }
  int e = e0 + base;
  for (; e + 3 < e1; e += 4) {           // deg>64 spillover (rare)
    int s = srt[e + sub];
    float4 g = G4[(size_t)s * 16 + fl];
    accA.x += g.x; accA.y += g.y; accA.z += g.z; accA.w += g.w;
  }
  int rem = e1 - e;                      // 0..3 remainder
  if (sub < rem) {
    int s = srt[e + sub];
    float4 g = G4[(size_t)s * 16 + fl];
    accA.x += g.x; accA.y += g.y; accA.z += g.z; accA.w += g.w;
  }

  float4 acc;
  acc.x = accA.x + accB.x; acc.y = accA.y + accB.y;
  acc.z = accA.z + accB.z; acc.w = accA.w + accB.w;
#pragma unroll
  for (int m = 16; m < 64; m <<= 1) {
    acc.x += __shfl_xor(acc.x, m, 64);
    acc.y += __shfl_xor(acc.y, m, 64);
    acc.z += __shfl_xor(acc.z, m, 64);
    acc.w += __shfl_xor(acc.w, m, 64);
  }
  if (sub == 0) {
    float dn = dinv[node];
    float4 bb = ((const float4*)bias)[fl];
    float4 r;
    r.x = fmaxf(fmaf(acc.x, dn, bb.x), 0.f);
    r.y = fmaxf(fmaf(acc.y, dn, bb.y), 0.f);
    r.z = fmaxf(fmaf(acc.z, dn, bb.z), 0.f);
    r.w = fmaxf(fmaf(acc.w, dn, bb.w), 0.f);
    ((float4*)H)[(size_t)node * 16 + fl] = r;
  }
}

// ---------------- classifier: part[b][c] = block-partial of sum_i H[i]*Wc[i*6+c] --------
// LCM(4,6)=12: each thread owns 12 consecutive Wc floats (2 rows, 3x float4) + float2 of H.
// NO atomics: per-block partials, reduced by reduce_softmax (round-3: atomic tail was 160us).

__global__ __launch_bounds__(256) void classifier(
    const float* __restrict__ H, const float* __restrict__ Wc,
    float* __restrict__ part, int M12) {
  float a[6] = {0.f, 0.f, 0.f, 0.f, 0.f, 0.f};
  int stride = gridDim.x * blockDim.x;
  for (int g = blockIdx.x * blockDim.x + threadIdx.x; g < M12; g += stride) {
    const float4* w4 = (const float4*)Wc + (size_t)g * 3;
    float4 v0 = w4[0];
    float4 v1 = w4[1];
    float4 v2 = w4[2];
    float2 h = ((const float2*)H)[g];
    a[0] = fmaf(h.x, v0.x, a[0]); a[1] = fmaf(h.x, v0.y, a[1]);
    a[2] = fmaf(h.x, v0.z, a[2]); a[3] = fmaf(h.x, v0.w, a[3]);
    a[4] = fmaf(h.x, v1.x, a[4]); a[5] = fmaf(h.x, v1.y, a[5]);
    a[0] = fmaf(h.y, v1.z, a[0]); a[1] = fmaf(h.y, v1.w, a[1]);
    a[2] = fmaf(h.y, v2.x, a[2]); a[3] = fmaf(h.y, v2.y, a[3]);
    a[4] = fmaf(h.y, v2.z, a[4]); a[5] = fmaf(h.y, v2.w, a[5]);
  }
#pragma unroll
  for (int c = 0; c < 6; ++c) {
    for (int d = 32; d > 0; d >>= 1) a[c] += __shfl_down(a[c], d, 64);
  }
  __shared__ float sh[4][6];
  int lane = threadIdx.x & 63, wv = threadIdx.x >> 6;
  if (lane == 0) {
#pragma unroll
    for (int c = 0; c < 6; ++c) sh[wv][c] = a[c];
  }
  __syncthreads();
  if (threadIdx.x == 0) {
#pragma unroll
    for (int c = 0; c < 6; ++c)
      part[(size_t)blockIdx.x * 6 + c] = sh[0][c] + sh[1][c] + sh[2][c] + sh[3][c];
  }
}

// single block: sum part[nb][6], add bias, softmax, write out[6]
__global__ __launch_bounds__(256) void reduce_softmax(
    const float* __restrict__ part, int nb,
    const float* __restrict__ bc, float* __restrict__ out) {
  int tid = threadIdx.x, lane = tid & 63, wv = tid >> 6;
  float a[6] = {0.f, 0.f, 0.f, 0.f, 0.f, 0.f};
  for (int b = tid; b < nb; b += 256) {
    const float* p = part + (size_t)b * 6;
#pragma unroll
    for (int c = 0; c < 6; ++c) a[c] += p[c];
  }
#pragma unroll
  for (int c = 0; c < 6; ++c) {
    for (int d = 32; d > 0; d >>= 1) a[c] += __shfl_down(a[c], d, 64);
  }
  __shared__ float sh[4][6];
  if (lane == 0) {
#pragma unroll
    for (int c = 0; c < 6; ++c) sh[wv][c] = a[c];
  }
  __syncthreads();
  if (tid == 0) {
    float l[6], m = -1e30f;
#pragma unroll
    for (int c = 0; c < 6; ++c) {
      l[c] = sh[0][c] + sh[1][c] + sh[2][c] + sh[3][c] + bc[c];
      m = fmaxf(m, l[c]);
    }
    float s = 0.f;
#pragma unroll
    for (int c = 0; c < 6; ++c) { l[c] = __expf(l[c] - m); s += l[c]; }
    float inv = 1.f / s;
#pragma unroll
    for (int c = 0; c < 6; ++c) out[c] = l[c] * inv;
  }
}

// ---------------- launch ----------------

static inline size_t align4up(size_t x) { return (x + 3) & ~(size_t)3; }  // 4-elem = 16B

extern "C" void kernel_launch(void* const* d_in, const int* in_sizes, int n_in,
                              void* d_out, int out_size, void* d_ws, size_t ws_size,
                              hipStream_t stream) {
  const float* x  = (const float*)d_in[0];
  const int*   ei = (const int*)d_in[1];
  const float* W1 = (const float*)d_in[2];
  const float* b1 = (const float*)d_in[3];
  const float* W2 = (const float*)d_in[4];
  const float* b2 = (const float*)d_in[5];
  const float* Wc = (const float*)d_in[6];
  const float* bc = (const float*)d_in[7];
  float* out = (float*)d_out;

  const int N = in_sizes[0] / 128;  // 50000
  const int E = in_sizes[1] / 2;    // 800000
  const int* esrc = ei;
  const int* edst = ei + E;
  const int NR = (N + 1023) >> RBITS;  // 49 ranges (<= NR_MAX)
  const int CGRID = 2048;              // classifier blocks

  // 16B-aligned workspace carve
  size_t o = 0;
  int* offs   = (int*)d_ws + o;           o = align4up(o + N + 1);
  int* srt    = (int*)d_ws + o;           o = align4up(o + E);
  float* dinv = (float*)d_ws + o;         o = align4up(o + N);
  int* ghist  = (int*)d_ws + o;           o = align4up(o + (size_t)NR * NCH);
  float* bufA = (float*)d_ws + o;         o = align4up(o + (size_t)N * 64);
  float* bufB = (float*)d_ws + o;         o = align4up(o + (size_t)N * 64);
  float* part = (float*)d_ws + o;         o = align4up(o + (size_t)CGRID * 6);
  int2* ebuf  = (int2*)bufB;  // aliases bufB: dead after csr_range, bufB written by agg1

  hist_ranges<<<NCH, 256, 0, stream>>>(edst, ghist, NR, E);
  scan_ghist<<<1, 1024, 0, stream>>>(ghist, NR * NCH);
  scatter_ranges<<<NCH, 256, 0, stream>>>(esrc, edst, ghist, ebuf, NR, E);
  csr_range<<<NR, 1024, 0, stream>>>(ebuf, ghist, offs, srt, dinv, N, E, NR);

  gemm_scale<128, 32><<<(N + 31) / 32, 256, 0, stream>>>(x, W1, dinv, bufA, N);
  aggregate<<<(N + 3) / 4, 256, 0, stream>>>(bufA, offs, srt, dinv, b1, bufB, N);
  gemm_scale<64, 32><<<(N + 31) / 32, 256, 0, stream>>>(bufB, W2, dinv, bufA, N);
  aggregate<<<(N + 3) / 4, 256, 0, stream>>>(bufA, offs, srt, dinv, b2, bufB, N);

  // M12 = (N*64*6)/12 = N*32 groups of 12 Wc floats
  classifier<<<CGRID, 256, 0, stream>>>(bufB, Wc, part, N * 32);
  reduce_softmax<<<1, 256, 0, stream>>>(part, CGRID, bc, out);
}

// Round 9
// 165.878 us; speedup vs baseline: 2.2169x; 1.1427x over previous
//
#include <hip/hip_runtime.h>
#include <math.h>

// SensorGNN: 2-layer GCN (N=50000, E=800000, F=128, H=64) + flat classifier (6 classes).
// Graph build = counting sort by dst-range (radix 1024-node ranges):
//   hist_ranges -> scan_ghist -> scatter_ranges -> csr_range (dinv/offs/srt).
// Then [gemm+dinv-scale -> bf16 G -> csr-aggregate]x2 -> classifier partials -> reduce+softmax.
// Round-3 lesson: same-line global atomics serialize cross-XCD -> two-stage reduce.
// Round-4/5 lesson: random global atomic scatter bounces cache lines via HBM; ILP can't fix.
// Round-6 lesson: range partition w/ edge replication = 11% occupancy regression.
// Round-7/8 lesson: three different aggregate structures all ~57us -> random-row gather
//   throughput limit (~3.8 TB/s on 4-line rows). Only bytes/row cuts it: G stored bf16
//   (128B rows, 2 lines), f32 accumulation. H stays f32 (threshold margin ~4x).

#define NCH 256          // edge chunk blocks
#define RBITS 10         // range = 1024 nodes
#define NR_MAX 64

__device__ __forceinline__ ushort f32_to_bf16(float f) {  // RTN-even
  unsigned u = __float_as_uint(f);
  return (ushort)((u + 0x7fffu + ((u >> 16) & 1u)) >> 16);
}
__device__ __forceinline__ float bf16_to_f32(ushort h) {
  return __uint_as_float(((unsigned)h) << 16);
}

// ---------------- pass A: per-chunk range histograms ----------------

__global__ __launch_bounds__(256) void hist_ranges(
    const int* __restrict__ dst, int* __restrict__ ghist, int NR, int E) {
  __shared__ int h[NR_MAX];
  int tid = threadIdx.x, c = blockIdx.x;
  if (tid < NR) h[tid] = 0;
  __syncthreads();
  int E4 = E >> 2;
  int CH4 = (E4 + NCH - 1) / NCH;
  int i0 = c * CH4, i1 = min(i0 + CH4, E4);
  const int4* d4 = (const int4*)dst;
  for (int i = i0 + tid; i < i1; i += 256) {
    int4 d = d4[i];
    atomicAdd(&h[d.x >> RBITS], 1);
    atomicAdd(&h[d.y >> RBITS], 1);
    atomicAdd(&h[d.z >> RBITS], 1);
    atomicAdd(&h[d.w >> RBITS], 1);
  }
  if (c == NCH - 1) {
    for (int e = (E4 << 2) + tid; e < E; e += 256) atomicAdd(&h[dst[e] >> RBITS], 1);
  }
  __syncthreads();
  if (tid < NR) ghist[tid * NCH + c] = h[tid];  // range-major, chunk-minor
}

// ---------------- pass B: exclusive scan of ghist[NR*NCH] (single block) ----------------

__global__ __launch_bounds__(1024) void scan_ghist(int* __restrict__ g, int M) {
  __shared__ int wtot[16];
  int tid = threadIdx.x, lane = tid & 63, wv = tid >> 6;
  int SEG = (M + 1023) >> 10;
  int base = tid * SEG;
  int s = 0;
  for (int k = 0; k < SEG; ++k) { int i = base + k; if (i < M) s += g[i]; }
  int x = s;
#pragma unroll
  for (int d = 1; d < 64; d <<= 1) { int y = __shfl_up(x, d, 64); if (lane >= d) x += y; }
  if (lane == 63) wtot[wv] = x;
  __syncthreads();
  if (wv == 0 && lane < 16) {
    int t = wtot[lane], xx = t;
#pragma unroll
    for (int d = 1; d < 16; d <<= 1) { int y = __shfl_up(xx, d, 64); if (lane >= d) xx += y; }
    wtot[lane] = xx - t;  // exclusive
  }
  __syncthreads();
  int run = x - s + wtot[wv];
  for (int k = 0; k < SEG; ++k) {
    int i = base + k;
    if (i < M) { int tmp = g[i]; g[i] = run; run += tmp; }
  }
}

// ---------------- pass C: scatter (src,dst) pairs into range-sorted ebuf ----------------

__global__ __launch_bounds__(256) void scatter_ranges(
    const int* __restrict__ src, const int* __restrict__ dst,
    const int* __restrict__ ghist, int2* __restrict__ ebuf, int NR, int E) {
  __shared__ int cur[NR_MAX];
  int tid = threadIdx.x, c = blockIdx.x;
  if (tid < NR) cur[tid] = ghist[tid * NCH + c];
  __syncthreads();
  int E4 = E >> 2;
  int CH4 = (E4 + NCH - 1) / NCH;
  int i0 = c * CH4, i1 = min(i0 + CH4, E4);
  const int4* d4 = (const int4*)dst;
  const int4* s4 = (const int4*)src;
  for (int i = i0 + tid; i < i1; i += 256) {
    int4 d = d4[i];
    int4 s = s4[i];
    ebuf[atomicAdd(&cur[d.x >> RBITS], 1)] = make_int2(s.x, d.x);
    ebuf[atomicAdd(&cur[d.y >> RBITS], 1)] = make_int2(s.y, d.y);
    ebuf[atomicAdd(&cur[d.z >> RBITS], 1)] = make_int2(s.z, d.z);
    ebuf[atomicAdd(&cur[d.w >> RBITS], 1)] = make_int2(s.w, d.w);
  }
  if (c == NCH - 1) {
    for (int e = (E4 << 2) + tid; e < E; e += 256)
      ebuf[atomicAdd(&cur[dst[e] >> RBITS], 1)] = make_int2(src[e], dst[e]);
  }
}

// ---------------- pass D: per-range CSR build (dinv, offs, srt) ----------------

__global__ __launch_bounds__(1024) void csr_range(
    const int2* __restrict__ ebuf, const int* __restrict__ ghist,
    int* __restrict__ offs, int* __restrict__ srt, float* __restrict__ dinv,
    int N, int E, int NR) {
  __shared__ int hist[1024];
  __shared__ int wtot[16];
  int r = blockIdx.x;
  int lo = r << RBITS;
  int len = min(1024, N - lo);
  int tid = threadIdx.x, lane = tid & 63, wv = tid >> 6;
  int S  = ghist[r * NCH];
  int S1 = (r + 1 < NR) ? ghist[(r + 1) * NCH] : E;
  if (tid < len) hist[tid] = 0;
  __syncthreads();
  for (int i = S + tid; i < S1; i += 1024) atomicAdd(&hist[ebuf[i].y - lo], 1);
  __syncthreads();
  int v = (tid < len) ? hist[tid] : 0;
  if (tid < len) dinv[lo + tid] = rsqrtf((float)(v + 1));  // +1 self loop
  // exclusive scan of v across 1024 threads
  int x = v;
#pragma unroll
  for (int d = 1; d < 64; d <<= 1) { int y = __shfl_up(x, d, 64); if (lane >= d) x += y; }
  if (lane == 63) wtot[wv] = x;
  __syncthreads();  // also guarantees all hist reads (v) complete before cursor overwrite
  if (wv == 0 && lane < 16) {
    int t = wtot[lane], xx = t;
#pragma unroll
    for (int d = 1; d < 16; d <<= 1) { int y = __shfl_up(xx, d, 64); if (lane >= d) xx += y; }
    wtot[lane] = xx - t;
  }
  __syncthreads();
  int excl = x - v + wtot[wv];
  if (tid < len) {
    offs[lo + tid] = S + excl;
    hist[tid] = S + excl;  // reuse as cursor
  }
  if (r == 0 && tid == 0) offs[N] = E;
  __syncthreads();
  for (int i = S + tid; i < S1; i += 1024) {
    int2 e = ebuf[i];
    srt[atomicAdd(&hist[e.y - lo], 1)] = e.x;
  }
}

// ---------------- dense transform: Gb = bf16((X @ W) * dinv[row]) ----------------
// block = 256 (4 waves), 32 rows/block, each wave computes 8 rows x 64 cols.
// Unroll capped at 4 to avoid the round-1 VGPR blowup (256 VGPR + 380MB scratch spill).

template <int K, int ROWS>
__global__ __launch_bounds__(256) void gemm_scale(
    const float* __restrict__ X, const float* __restrict__ W,
    const float* __restrict__ dinv, ushort* __restrict__ Gb, int N) {
  __shared__ float smw[K * 64];
  __shared__ float xs[ROWS * K];
  int tid = threadIdx.x, lane = tid & 63, wv = tid >> 6;
  for (int idx = tid; idx < K * 16; idx += 256)
    ((float4*)smw)[idx] = ((const float4*)W)[idx];
  int row0 = blockIdx.x * ROWS;
  int base = row0 * K;
  int cnt4 = (min(ROWS * K, N * K - base)) >> 2;  // K%4==0 so exact
  const float4* X4 = (const float4*)(X + base);
  for (int idx = tid; idx < cnt4; idx += 256) ((float4*)xs)[idx] = X4[idx];
  __syncthreads();

  constexpr int RW = ROWS / 4;  // rows per wave
  float acc[RW];
#pragma unroll
  for (int r = 0; r < RW; ++r) acc[r] = 0.f;
  const float* xr = &xs[(wv * RW) * K];
#pragma unroll 4
  for (int k = 0; k < K; ++k) {
    float wval = smw[k * 64 + lane];  // lane-contiguous: 2-way bank alias = free
#pragma unroll
    for (int r = 0; r < RW; ++r) acc[r] = fmaf(xr[r * K + k], wval, acc[r]);  // LDS broadcast
  }
#pragma unroll
  for (int r = 0; r < RW; ++r) {
    int row = row0 + wv * RW + r;
    if (row < N) Gb[(size_t)row * 64 + lane] = f32_to_bf16(acc[r] * dinv[row]);
  }
}

// ---------------- aggregation: H[d] = relu(dinv[d]*(G[d] + sum_{s in in(d)} G[s]) + b) ----
// one wave per node. lane = sub*16 + fl. Edge indices for deg<=64 hoisted into registers
// (one coalesced srt load) and distributed via dynamic __shfl. G rows are bf16 (128B =
// 2 cache lines): lane reads ushort4 (4 feats), converts, accumulates f32.

__global__ __launch_bounds__(256) void aggregate(
    const ushort* __restrict__ Gb, const int* __restrict__ offs,
    const int* __restrict__ srt, const float* __restrict__ dinv,
    const float* __restrict__ bias, float* __restrict__ H, int N) {
  int lane = threadIdx.x & 63, wv = threadIdx.x >> 6;
  int sub = lane >> 4, fl = lane & 15;
  int node = blockIdx.x * 4 + wv;
  if (node >= N) return;
  const ushort4* G2 = (const ushort4*)Gb;  // 16 x ushort4 per 64-feat row

  int e0 = offs[node], e1 = offs[node + 1];
  int deg = e1 - e0;

  float4 accA = make_float4(0.f, 0.f, 0.f, 0.f);
  float4 accB = make_float4(0.f, 0.f, 0.f, 0.f);
  if (sub == 0) {  // self loop
    ushort4 q = G2[(size_t)node * 16 + fl];
    accA.x = bf16_to_f32(q.x); accA.y = bf16_to_f32(q.y);
    accA.z = bf16_to_f32(q.z); accA.w = bf16_to_f32(q.w);
  }

  // hoist up to 64 edge indices into registers (coalesced; covers ~all nodes, mean deg 16)
  int pre = (deg > 0) ? srt[e0 + min(lane, deg - 1)] : 0;

  int dcap = min(deg, 64);
  int base = 0;
  for (; base + 7 < dcap; base += 8) {   // 8 rows in flight, no index-load chain
    int sA = __shfl(pre, base + sub, 64);
    int sB = __shfl(pre, base + 4 + sub, 64);
    ushort4 qA = G2[(size_t)sA * 16 + fl];
    ushort4 qB = G2[(size_t)sB * 16 + fl];
    accA.x += bf16_to_f32(qA.x); accA.y += bf16_to_f32(qA.y);
    accA.z += bf16_to_f32(qA.z); accA.w += bf16_to_f32(qA.w);
    accB.x += bf16_to_f32(qB.x); accB.y += bf16_to_f32(qB.y);
    accB.z += bf16_to_f32(qB.z); accB.w += bf16_to_f32(qB.w);
  }
  for (; base + 3 < dcap; base += 4) {
    int s = __shfl(pre, base + sub, 64);
    ushort4 q = G2[(size_t)s * 16 + fl];
    accA.x += bf16_to_f32(q.x); accA.y += bf16_to_f32(q.y);
    accA.z += bf16_to_f32(q.z); accA.w += bf16_to_f32(q.w);
  }
  int e = e0 + base;
  for (; e + 3 < e1; e += 4) {           // deg>64 spillover (rare)
    int s = srt[e + sub];
    ushort4 q = G2[(size_t)s * 16 + fl];
    accA.x += bf16_to_f32(q.x); accA.y += bf16_to_f32(q.y);
    accA.z += bf16_to_f32(q.z); accA.w += bf16_to_f32(q.w);
  }
  int rem = e1 - e;                      // 0..3 remainder
  if (sub < rem) {
    int s = srt[e + sub];
    ushort4 q = G2[(size_t)s * 16 + fl];
    accA.x += bf16_to_f32(q.x); accA.y += bf16_to_f32(q.y);
    accA.z += bf16_to_f32(q.z); accA.w += bf16_to_f32(q.w);
  }

  float4 acc;
  acc.x = accA.x + accB.x; acc.y = accA.y + accB.y;
  acc.z = accA.z + accB.z; acc.w = accA.w + accB.w;
#pragma unroll
  for (int m = 16; m < 64; m <<= 1) {
    acc.x += __shfl_xor(acc.x, m, 64);
    acc.y += __shfl_xor(acc.y, m, 64);
    acc.z += __shfl_xor(acc.z, m, 64);
    acc.w += __shfl_xor(acc.w, m, 64);
  }
  if (sub == 0) {
    float dn = dinv[node];
    float4 bb = ((const float4*)bias)[fl];
    float4 r;
    r.x = fmaxf(fmaf(acc.x, dn, bb.x), 0.f);
    r.y = fmaxf(fmaf(acc.y, dn, bb.y), 0.f);
    r.z = fmaxf(fmaf(acc.z, dn, bb.z), 0.f);
    r.w = fmaxf(fmaf(acc.w, dn, bb.w), 0.f);
    ((float4*)H)[(size_t)node * 16 + fl] = r;
  }
}

// ---------------- classifier: part[b][c] = block-partial of sum_i H[i]*Wc[i*6+c] --------
// LCM(4,6)=12: each thread owns 12 consecutive Wc floats (2 rows, 3x float4) + float2 of H.
// NO atomics: per-block partials, reduced by reduce_softmax (round-3: atomic tail was 160us).

__global__ __launch_bounds__(256) void classifier(
    const float* __restrict__ H, const float* __restrict__ Wc,
    float* __restrict__ part, int M12) {
  float a[6] = {0.f, 0.f, 0.f, 0.f, 0.f, 0.f};
  int stride = gridDim.x * blockDim.x;
  for (int g = blockIdx.x * blockDim.x + threadIdx.x; g < M12; g += stride) {
    const float4* w4 = (const float4*)Wc + (size_t)g * 3;
    float4 v0 = w4[0];
    float4 v1 = w4[1];
    float4 v2 = w4[2];
    float2 h = ((const float2*)H)[g];
    a[0] = fmaf(h.x, v0.x, a[0]); a[1] = fmaf(h.x, v0.y, a[1]);
    a[2] = fmaf(h.x, v0.z, a[2]); a[3] = fmaf(h.x, v0.w, a[3]);
    a[4] = fmaf(h.x, v1.x, a[4]); a[5] = fmaf(h.x, v1.y, a[5]);
    a[0] = fmaf(h.y, v1.z, a[0]); a[1] = fmaf(h.y, v1.w, a[1]);
    a[2] = fmaf(h.y, v2.x, a[2]); a[3] = fmaf(h.y, v2.y, a[3]);
    a[4] = fmaf(h.y, v2.z, a[4]); a[5] = fmaf(h.y, v2.w, a[5]);
  }
#pragma unroll
  for (int c = 0; c < 6; ++c) {
    for (int d = 32; d > 0; d >>= 1) a[c] += __shfl_down(a[c], d, 64);
  }
  __shared__ float sh[4][6];
  int lane = threadIdx.x & 63, wv = threadIdx.x >> 6;
  if (lane == 0) {
#pragma unroll
    for (int c = 0; c < 6; ++c) sh[wv][c] = a[c];
  }
  __syncthreads();
  if (threadIdx.x == 0) {
#pragma unroll
    for (int c = 0; c < 6; ++c)
      part[(size_t)blockIdx.x * 6 + c] = sh[0][c] + sh[1][c] + sh[2][c] + sh[3][c];
  }
}

// single block: sum part[nb][6], add bias, softmax, write out[6]
__global__ __launch_bounds__(256) void reduce_softmax(
    const float* __restrict__ part, int nb,
    const float* __restrict__ bc, float* __restrict__ out) {
  int tid = threadIdx.x, lane = tid & 63, wv = tid >> 6;
  float a[6] = {0.f, 0.f, 0.f, 0.f, 0.f, 0.f};
  for (int b = tid; b < nb; b += 256) {
    const float* p = part + (size_t)b * 6;
#pragma unroll
    for (int c = 0; c < 6; ++c) a[c] += p[c];
  }
#pragma unroll
  for (int c = 0; c < 6; ++c) {
    for (int d = 32; d > 0; d >>= 1) a[c] += __shfl_down(a[c], d, 64);
  }
  __shared__ float sh[4][6];
  if (lane == 0) {
#pragma unroll
    for (int c = 0; c < 6; ++c) sh[wv][c] = a[c];
  }
  __syncthreads();
  if (tid == 0) {
    float l[6], m = -1e30f;
#pragma unroll
    for (int c = 0; c < 6; ++c) {
      l[c] = sh[0][c] + sh[1][c] + sh[2][c] + sh[3][c] + bc[c];
      m = fmaxf(m, l[c]);
    }
    float s = 0.f;
#pragma unroll
    for (int c = 0; c < 6; ++c) { l[c] = __expf(l[c] - m); s += l[c]; }
    float inv = 1.f / s;
#pragma unroll
    for (int c = 0; c < 6; ++c) out[c] = l[c] * inv;
  }
}

// ---------------- launch ----------------

static inline size_t align4up(size_t x) { return (x + 3) & ~(size_t)3; }  // 4-elem = 16B

extern "C" void kernel_launch(void* const* d_in, const int* in_sizes, int n_in,
                              void* d_out, int out_size, void* d_ws, size_t ws_size,
                              hipStream_t stream) {
  const float* x  = (const float*)d_in[0];
  const int*   ei = (const int*)d_in[1];
  const float* W1 = (const float*)d_in[2];
  const float* b1 = (const float*)d_in[3];
  const float* W2 = (const float*)d_in[4];
  const float* b2 = (const float*)d_in[5];
  const float* Wc = (const float*)d_in[6];
  const float* bc = (const float*)d_in[7];
  float* out = (float*)d_out;

  const int N = in_sizes[0] / 128;  // 50000
  const int E = in_sizes[1] / 2;    // 800000
  const int* esrc = ei;
  const int* edst = ei + E;
  const int NR = (N + 1023) >> RBITS;  // 49 ranges (<= NR_MAX)
  const int CGRID = 2048;              // classifier blocks

  // 16B-aligned workspace carve
  size_t o = 0;
  int* offs   = (int*)d_ws + o;           o = align4up(o + N + 1);
  int* srt    = (int*)d_ws + o;           o = align4up(o + E);
  float* dinv = (float*)d_ws + o;         o = align4up(o + N);
  int* ghist  = (int*)d_ws + o;           o = align4up(o + (size_t)NR * NCH);
  ushort* Gb  = (ushort*)((int*)d_ws + o); o = align4up(o + (size_t)N * 32);  // N*64 bf16
  float* bufB = (float*)d_ws + o;         o = align4up(o + (size_t)N * 64);
  float* part = (float*)d_ws + o;         o = align4up(o + (size_t)CGRID * 6);
  int2* ebuf  = (int2*)bufB;  // aliases bufB: dead after csr_range, bufB written by agg1

  hist_ranges<<<NCH, 256, 0, stream>>>(edst, ghist, NR, E);
  scan_ghist<<<1, 1024, 0, stream>>>(ghist, NR * NCH);
  scatter_ranges<<<NCH, 256, 0, stream>>>(esrc, edst, ghist, ebuf, NR, E);
  csr_range<<<NR, 1024, 0, stream>>>(ebuf, ghist, offs, srt, dinv, N, E, NR);

  gemm_scale<128, 32><<<(N + 31) / 32, 256, 0, stream>>>(x, W1, dinv, Gb, N);
  aggregate<<<(N + 3) / 4, 256, 0, stream>>>(Gb, offs, srt, dinv, b1, bufB, N);
  gemm_scale<64, 32><<<(N + 31) / 32, 256, 0, stream>>>(bufB, W2, dinv, Gb, N);
  aggregate<<<(N + 3) / 4, 256, 0, stream>>>(Gb, offs, srt, dinv, b2, bufB, N);

  // M12 = (N*64*6)/12 = N*32 groups of 12 Wc floats
  classifier<<<CGRID, 256, 0, stream>>>(bufB, Wc, part, N * 32);
  reduce_softmax<<<1, 256, 0, stream>>>(part, CGRID, bc, out);
}